// Round 4
// baseline (120.029 us; speedup 1.0000x reference)
//
#include <hip/hip_runtime.h>
#include <math.h>

// Chamfer distance, B=4, H=W=128, HW=16384, threshold 0.1.
// ws layout:
//   [0,128)   int segcounts[8][4]   (plain stores, no memset needed)
//   [256, 256+8*HW*16)   float4 pts[8][HW]   segmented semi-dense:
//                        combo's seg s actives at [s*4096, s*4096+cnt)
//   [+2MB, +2MB+8*HW*4)  uint  minarr[8][HW] (d^2 bits, slot-indexed, atomicMin)
//
// r3 post-mortem: total == fill(43us harness ws-poison, fixed) + dist-path +
// ~19us fixed. Removing atomics entirely (store+minc) changed NOTHING ->
// dist is VALU-ISSUE-bound (issue cycles ~2x the 2.5-op/pair static model,
// saturated at 83-92% busy, occupancy-insensitive). Only fewer instructions
// per pair helps: v_pk_fma_f32 (CDNA full-rate packed fp32, never emitted by
// hipcc) -> 1.5 VALU/pair. SoA LDS so column pairs land in VGPR pairs.

#define B_ 4
#define HW_ 16384
#define THRESH 0.1f
#define BIGF 1e30f
#define EPS_ 1e-12f

#define NTHR 512       // dist: 8 waves/block
#define RROWS 16       // rows/thread: covers 8192 row slots in one pass
#define NCHUNK 64      // 64 x 8 combos = 512 blocks = 2/CU
#define MAXCHUNK 256   // ceil(HW/NCHUNK); cpad <= 256 always
#define SEGCAP 4096    // elements per compaction segment
#define NSEG 4

typedef float f2 __attribute__((ext_vector_type(2)));

// v_pk_fma_f32: d = {a.lo*b.lo+c.lo, a.hi*b.hi+c.hi}. IEEE fma per half --
// identical rounding to v_fma_f32, so d^2 bits match the scalar version.
__device__ __forceinline__ f2 pk_fma(f2 a, f2 b, f2 c) {
    f2 d;
    asm("v_pk_fma_f32 %0, %1, %2, %3" : "=v"(d) : "v"(a), "v"(b), "v"(c));
    return d;
}

// Atomic-free compaction: one block per (segment, combo). 1024 thr x 4 elems,
// float4 loads; in-block prefix scan (wave shfl + LDS); actives written dense
// within the segment; per-seg count = plain store. minarr init via uint4.
__global__ __launch_bounds__(1024)
void compact_kernel(const float* __restrict__ in1, const float* __restrict__ in2,
                    int* __restrict__ segcounts, float4* __restrict__ pts,
                    uint4* __restrict__ minarr4) {
    int seg = blockIdx.x, combo = blockIdx.y;
    int b = combo >> 1, s = combo & 1;
    int tid = threadIdx.x, lane = tid & 63, wid = tid >> 6;
    const float* in = s ? in2 : in1;
    int ibase = seg * SEGCAP + tid * 4;              // element index in image
    float4 v = ((const float4*)(in + b * HW_))[(unsigned)ibase >> 2];
    float w0 = v.x - THRESH, w1 = v.y - THRESH, w2 = v.z - THRESH, w3 = v.w - THRESH;
    int a0 = w0 > 0.f, a1 = w1 > 0.f, a2 = w2 > 0.f, a3 = w3 > 0.f;

    unsigned int bb = __float_as_uint(BIGF);
    minarr4[(unsigned)(combo * HW_ + ibase) >> 2] = make_uint4(bb, bb, bb, bb);

    int c = a0 + a1 + a2 + a3;
    int incl = c;
#pragma unroll
    for (int o = 1; o < 64; o <<= 1) {
        int x = __shfl_up(incl, o, 64);
        if (lane >= o) incl += x;
    }
    int wexcl = incl - c;
    __shared__ int wtot[16], wpre[17];
    if (lane == 63) wtot[wid] = incl;
    __syncthreads();
    if (tid == 0) {
        int run = 0;
#pragma unroll
        for (int ww = 0; ww < 16; ++ww) { wpre[ww] = run; run += wtot[ww]; }
        wpre[16] = run;
    }
    __syncthreads();
    int off = wpre[wid] + wexcl;
    float4* dst = pts + combo * HW_ + seg * SEGCAP;
    float wv[4] = {w0, w1, w2, w3};
    int   av[4] = {a0, a1, a2, a3};
#pragma unroll
    for (int u = 0; u < 4; ++u) {
        if (av[u]) {
            int i = ibase + u;
            float qx = (float)(i >> 7) * wv[u];
            float qy = (float)(i & 127) * wv[u];
            dst[off] = make_float4(qx, qy, qx * qx + qy * qy, 0.0f);
            ++off;
        }
    }
    if (tid == 0) segcounts[combo * 4 + seg] = wpre[16];
}

// dense index r in [0, n) -> segmented slot, given prefix offsets o1<=o2<=o3.
__device__ __forceinline__ int map_slot(int r, int o1, int o2, int o3) {
    int slot = r;
    slot = (r >= o1) ? r - o1 + SEGCAP     : slot;
    slot = (r >= o2) ? r - o2 + 2 * SEGCAP : slot;
    slot = (r >= o3) ? r - o3 + 3 * SEGCAP : slot;
    return slot;
}

// grid (NCHUNK=64, 8 combos), 512 threads = 2 blocks/CU. Stage this block's
// to-chunk into SoA LDS (bufx/bufy/bufz, 3KB, sentinel-padded to x4); each
// thread min-reduces RROWS=16 rows against it with PACKED math: per 4 cols
// per row, 4 v_pk_fma_f32 + 2 v_min3 = 1.5 VALU/pair (vs 2.5 scalar). Row
// constants -2px/-2py pre-splat into f2 regs. Cross-chunk combine via uint
// atomicMin on d^2 bits (r3 proved atomics are NOT the wall; one kernel).
__global__ __launch_bounds__(NTHR, 4)   // VGPR cap 128: ~100 needed, no spill
void dist_kernel(const int* __restrict__ segcounts,
                 const float4* __restrict__ pts,
                 unsigned int* __restrict__ minarr) {
    int chunk = blockIdx.x;
    int combo = blockIdx.y;
    int tid = threadIdx.x;
    int tc = combo ^ 1;
    int f1 = segcounts[combo * 4];
    int f2_ = f1 + segcounts[combo * 4 + 1];
    int f3 = f2_ + segcounts[combo * 4 + 2];
    int n_from = f3 + segcounts[combo * 4 + 3];
    int t1 = segcounts[tc * 4];
    int t2 = t1 + segcounts[tc * 4 + 1];
    int t3 = t2 + segcounts[tc * 4 + 2];
    int n_to = t3 + segcounts[tc * 4 + 3];
    if (n_from <= 0 || n_to <= 0) return;

    int len   = (n_to + NCHUNK - 1) / NCHUNK;
    int start = chunk * len;
    int end   = min(start + len, n_to);
    int clen  = end - start;
    if (clen <= 0) return;                       // block-uniform, before any sync
    int cpad  = (clen + 3) & ~3;                 // <= MAXCHUNK always

    const float4* __restrict__ to   = pts + tc * HW_;
    const float4* __restrict__ from = pts + combo * HW_;

    __shared__ __align__(16) float bufx[MAXCHUNK];
    __shared__ __align__(16) float bufy[MAXCHUNK];
    __shared__ __align__(16) float bufz[MAXCHUNK];
    if (tid < clen) {
        float4 q = to[map_slot(start + tid, t1, t2, t3)];
        bufx[tid] = q.x; bufy[tid] = q.y; bufz[tid] = q.z;
    } else if (tid < cpad) {
        bufx[tid] = 0.0f; bufy[tid] = 0.0f; bufz[tid] = BIGF;  // never the min
    }
    __syncthreads();

    for (int rbase = 0; rbase < n_from; rbase += NTHR * RROWS) {  // 1 iter here
        f2 bx[RROWS], by[RROWS];
        float m[RROWS];
#pragma unroll
        for (int k = 0; k < RROWS; ++k) {
            int r = min(rbase + tid + k * NTHR, n_from - 1);  // clamp -> valid
            float4 p = from[map_slot(r, f1, f2_, f3)];
            bx[k] = (f2)(-2.0f * p.x);           // splat into both halves
            by[k] = (f2)(-2.0f * p.y);
            m[k]  = BIGF;
        }
        for (int j = 0; j < cpad; j += 4) {      // 4 cols: 3x ds_read_b128
            f2 x01 = *(const f2*)&bufx[j];       // uniform addr -> broadcast
            f2 x23 = *(const f2*)&bufx[j + 2];
            f2 y01 = *(const f2*)&bufy[j];
            f2 y23 = *(const f2*)&bufy[j + 2];
            f2 z01 = *(const f2*)&bufz[j];
            f2 z23 = *(const f2*)&bufz[j + 2];
#pragma unroll
            for (int k = 0; k < RROWS; ++k) {
                f2 a = pk_fma(y01, by[k], z01);  // z + y*(-2py)
                a    = pk_fma(x01, bx[k], a);    // + x*(-2px)
                m[k] = fminf(m[k], fminf(a[0], a[1]));   // -> v_min3_f32
                f2 b = pk_fma(y23, by[k], z23);
                b    = pk_fma(x23, bx[k], b);
                m[k] = fminf(m[k], fminf(b[0], b[1]));
            }
        }
#pragma unroll
        for (int k = 0; k < RROWS; ++k) {
            int rd = rbase + tid + k * NTHR;
            if (rd < n_from) {
                int slot = map_slot(rd, f1, f2_, f3);
                float p2 = from[slot].z;         // |p|^2 re-read (saves 16 regs)
                float d2 = fmaxf(m[k] + p2, 0.0f);
                atomicMin(&minarr[combo * HW_ + slot], __float_as_uint(d2));
            }
        }
    }
}

// One 1024-thread block per batch; both directions reduced concurrently
// (tid<512 -> dir0, else dir1). Iterates segments directly (slot-indexed).
// UNCHANGED: summation order defines the absmax==0.0 baseline.
__global__ void reduce_out_kernel(const int* __restrict__ segcounts,
                                  const unsigned int* __restrict__ minarr,
                                  float* __restrict__ out) {
    int b = blockIdx.x;
    int tid = threadIdx.x;
    int d = tid >> 9;                            // 0 or 1
    int t = tid & 511;
    int combo = b * 2 + d;

    float acc = 0.0f;
    for (int s = 0; s < NSEG; ++s) {
        int c = segcounts[combo * 4 + s];
        const unsigned int* ma = minarr + combo * HW_ + s * SEGCAP;
        for (int r = t; r < c; r += 512)
            acc += sqrtf(fmaxf(__uint_as_float(ma[r]), EPS_));
    }
#pragma unroll
    for (int o = 32; o >= 1; o >>= 1) acc += __shfl_down(acc, o);

    __shared__ float wsum[16];                   // waves 0-7 dir0, 8-15 dir1
    if ((tid & 63) == 0) wsum[tid >> 6] = acc;
    __syncthreads();
    if (tid == 0) {
        float s0 = 0.0f, s1 = 0.0f;
#pragma unroll
        for (int w = 0; w < 8; ++w)  s0 += wsum[w];
#pragma unroll
        for (int w = 8; w < 16; ++w) s1 += wsum[w];
        int n0 = 0, n1 = 0;
#pragma unroll
        for (int s = 0; s < NSEG; ++s) {
            n0 += segcounts[(b * 2) * 4 + s];
            n1 += segcounts[(b * 2 + 1) * 4 + s];
        }
        out[b] = (n0 > 0 && n1 > 0)
                 ? s0 / (float)n0 + s1 / (float)n1
                 : 1.0e6f;
    }
}

extern "C" void kernel_launch(void* const* d_in, const int* in_sizes, int n_in,
                              void* d_out, int out_size, void* d_ws, size_t ws_size,
                              hipStream_t stream) {
    const float* in1 = (const float*)d_in[0];
    const float* in2 = (const float*)d_in[1];
    float* out = (float*)d_out;
    char* ws = (char*)d_ws;
    int* segcounts = (int*)ws;
    float4* pts = (float4*)(ws + 256);
    unsigned int* minarr = (unsigned int*)(ws + 256 + (size_t)8 * HW_ * sizeof(float4));

    hipLaunchKernelGGL(compact_kernel, dim3(NSEG, 8), dim3(1024), 0, stream,
                       in1, in2, segcounts, pts, (uint4*)minarr);
    hipLaunchKernelGGL(dist_kernel, dim3(NCHUNK, 8), dim3(NTHR), 0, stream,
                       segcounts, pts, minarr);
    hipLaunchKernelGGL(reduce_out_kernel, dim3(B_), dim3(1024), 0, stream,
                       segcounts, minarr, out);
}

// Round 5
// 95.998 us; speedup vs baseline: 1.2503x; 1.2503x over previous
//
#include <hip/hip_runtime.h>
#include <math.h>

// Chamfer distance, B=4, H=W=128, HW=16384, threshold 0.1.
//
// r4 post-mortem: VALU busy-time constant 36-38us across scalar/SGPR/packed
// variants -> v_pk_fma_f32 is 2-pass on the 32-lane fp32 datapath (157.3TF
// vector peak IS the scalar ceiling); dense dist is at its fp32 roofline at
// 2.5 instr/pair. Only lever left: fewer pairs. This round: norm(rho)-sorted
// bucket layout + ring-bound pruning (d >= |rho_r - rho_c|), two-pointer
// 64-col batch expansion with wave-uniform termination. Pruned cols provably
// (1e3x margin over fp32 error) can't change the min -> minarr bits
// identical -> absmax 0.0. Rows resolved by ONE block each: plain stores.
//
// ws layout (~4.6 MB):
//   [0,128)    int segcounts[8][4]
//   [256,+2MB) float4 pts[8][HW]     segmented semi-dense (seg s at s*4096)
//   [+512KB)   uint minarr[8][HW]    d^2 bits, slot-indexed
//   [+2MB)     float4 sorted[8][HW]  (x, y, z, slot_bits) rho-bucket order
//   [+8.2KB)   int binstart[8][257]

#define B_ 4
#define HW_ 16384
#define THRESH 0.1f
#define BIGF 1e30f
#define EPS_ 1e-12f

#define SEGCAP 4096
#define NSEG 4
#define NBIN 256
#define BINSCALE 0.25f   // rho in [0, ~990] -> bin = min(255, rho*0.25)
#define PD_NGRP 128      // 128 groups x 128 rows covers n_from <= 16384

// ---------------- compact (unchanged from r2, proven) ----------------
__global__ __launch_bounds__(1024)
void compact_kernel(const float* __restrict__ in1, const float* __restrict__ in2,
                    int* __restrict__ segcounts, float4* __restrict__ pts,
                    uint4* __restrict__ minarr4) {
    int seg = blockIdx.x, combo = blockIdx.y;
    int b = combo >> 1, s = combo & 1;
    int tid = threadIdx.x, lane = tid & 63, wid = tid >> 6;
    const float* in = s ? in2 : in1;
    int ibase = seg * SEGCAP + tid * 4;
    float4 v = ((const float4*)(in + b * HW_))[(unsigned)ibase >> 2];
    float w0 = v.x - THRESH, w1 = v.y - THRESH, w2 = v.z - THRESH, w3 = v.w - THRESH;
    int a0 = w0 > 0.f, a1 = w1 > 0.f, a2 = w2 > 0.f, a3 = w3 > 0.f;

    unsigned int bb = __float_as_uint(BIGF);
    minarr4[(unsigned)(combo * HW_ + ibase) >> 2] = make_uint4(bb, bb, bb, bb);

    int c = a0 + a1 + a2 + a3;
    int incl = c;
#pragma unroll
    for (int o = 1; o < 64; o <<= 1) {
        int x = __shfl_up(incl, o, 64);
        if (lane >= o) incl += x;
    }
    int wexcl = incl - c;
    __shared__ int wtot[16], wpre[17];
    if (lane == 63) wtot[wid] = incl;
    __syncthreads();
    if (tid == 0) {
        int run = 0;
#pragma unroll
        for (int ww = 0; ww < 16; ++ww) { wpre[ww] = run; run += wtot[ww]; }
        wpre[16] = run;
    }
    __syncthreads();
    int off = wpre[wid] + wexcl;
    float4* dst = pts + combo * HW_ + seg * SEGCAP;
    float wv[4] = {w0, w1, w2, w3};
    int   av[4] = {a0, a1, a2, a3};
#pragma unroll
    for (int u = 0; u < 4; ++u) {
        if (av[u]) {
            int i = ibase + u;
            float qx = (float)(i >> 7) * wv[u];
            float qy = (float)(i & 127) * wv[u];
            dst[off] = make_float4(qx, qy, qx * qx + qy * qy, 0.0f);
            ++off;
        }
    }
    if (tid == 0) segcounts[combo * 4 + seg] = wpre[16];
}

// ---------------- sort: rho-bucket layout, 1 block/combo ----------------
__global__ __launch_bounds__(1024)
void sort_kernel(const int* __restrict__ segcounts, const float4* __restrict__ pts,
                 float4* __restrict__ sorted, int* __restrict__ binstart) {
    int combo = blockIdx.x;
    int tid = threadIdx.x;
    __shared__ unsigned int hist[NBIN];
    __shared__ unsigned int cur[NBIN];
    if (tid < NBIN) hist[tid] = 0;
    __syncthreads();
    // pass 1: histogram
    for (int s = 0; s < NSEG; ++s) {
        int c = segcounts[combo * 4 + s];
        const float4* seg = pts + combo * HW_ + s * SEGCAP;
        for (int i = tid; i < c; i += 1024) {
            float rho = sqrtf(seg[i].z);
            int bin = min(NBIN - 1, (int)(rho * BINSCALE));
            atomicAdd(&hist[bin], 1u);
        }
    }
    __syncthreads();
    if (tid == 0) {
        unsigned int run = 0;
        for (int bq = 0; bq < NBIN; ++bq) {
            cur[bq] = run;
            binstart[combo * (NBIN + 1) + bq] = (int)run;
            run += hist[bq];
        }
        binstart[combo * (NBIN + 1) + NBIN] = (int)run;   // == n_active
    }
    __syncthreads();
    // pass 2: scatter (order within bin nondeterministic -- min-invariant)
    for (int s = 0; s < NSEG; ++s) {
        int c = segcounts[combo * 4 + s];
        const float4* seg = pts + combo * HW_ + s * SEGCAP;
        for (int i = tid; i < c; i += 1024) {
            float4 p = seg[i];
            float rho = sqrtf(p.z);
            int bin = min(NBIN - 1, (int)(rho * BINSCALE));
            unsigned int idx = atomicAdd(&cur[bin], 1u);
            sorted[(size_t)combo * HW_ + idx] =
                make_float4(p.x, p.y, p.z, __uint_as_float((unsigned)(s * SEGCAP + i)));
        }
    }
}

// ---------------- pruned dist: 1 wave/block, 128 sorted rows ----------------
// Ring bound: d^2(r,c) >= (rho_r - rho_c)^2. Expand [jlo,jhi) in 64-col
// batches; stop a side when ALL rows satisfy (edge drho)^2*0.999-0.01 > md
// (margin ~1e3x the accumulated fp32 error of rho/t -> pruned cols provably
// exceed the final min). Inner t-formula copied VERBATIM from the dense
// kernel: same fma association, same min tree, same epilogue -> same bits.
__global__ __launch_bounds__(64)
void pdist_kernel(const float4* __restrict__ sorted, const int* __restrict__ binstart,
                  unsigned int* __restrict__ minarr) {
    int grp = blockIdx.x, combo = blockIdx.y;
    int lane = threadIdx.x;
    int tc = combo ^ 1;
    int n_from = binstart[combo * (NBIN + 1) + NBIN];
    int n_to   = binstart[tc * (NBIN + 1) + NBIN];
    if (n_from <= 0 || n_to <= 0) return;        // reduce_out emits sentinel
    int rbase = grp * 128;
    if (rbase >= n_from) return;                 // block-uniform

    const float4* __restrict__ rows = sorted + (size_t)combo * HW_;
    const float4* __restrict__ cols = sorted + (size_t)tc * HW_;

    int r0 = rbase + lane, r1 = rbase + 64 + lane;
    bool v0 = r0 < n_from, v1 = r1 < n_from;
    float4 P0 = rows[min(r0, n_from - 1)];
    float4 P1 = rows[min(r1, n_from - 1)];
    float npx0 = -2.0f * P0.x, npy0 = -2.0f * P0.y, p20 = P0.z, rho0 = sqrtf(P0.z);
    float npx1 = -2.0f * P1.x, npy1 = -2.0f * P1.y, p21 = P1.z, rho1 = sqrtf(P1.z);
    unsigned int slot0 = __float_as_uint(P0.w);
    unsigned int slot1 = __float_as_uint(P1.w);
    float m0 = BIGF, m1 = BIGF;

    // start near the group's mid-rho bin (uniform: same load on all lanes)
    float rmid = sqrtf(rows[min(rbase + 64, n_from - 1)].z);
    int bmid = min(NBIN - 1, (int)(rmid * BINSCALE));
    int jlo = min(binstart[tc * (NBIN + 1) + bmid], n_to);
    int jhi = jlo;
    bool doneL = (jlo == 0), doneR = (jhi >= n_to);

    __shared__ __align__(16) float bufx[64];
    __shared__ __align__(16) float bufy[64];
    __shared__ __align__(16) float bufz[64];
    const float4* X = (const float4*)bufx;
    const float4* Y = (const float4*)bufy;
    const float4* Z = (const float4*)bufz;

    for (int iter = 0; (!doneL || !doneR) && iter < 2 * (HW_ / 64) + 4; ++iter) {
        bool left;
        if (doneL) left = false;
        else if (doneR) left = true;
        else left = (iter & 1);

        int jb = left ? (jlo - 64) : jhi;        // batch = [jb, jb+64)
        int j = jb + lane;
        float4 q = (j >= 0 && j < n_to) ? cols[j]
                                        : make_float4(0.0f, 0.0f, BIGF, 0.0f);
        bufx[lane] = q.x; bufy[lane] = q.y; bufz[lane] = q.z;
        __syncthreads();                         // 1-wave block: just waitcnt

#pragma unroll
        for (int q4 = 0; q4 < 16; ++q4) {        // 4 cols: 3x ds_read_b128
            float4 qx = X[q4], qy = Y[q4], qz = Z[q4];
            // VERBATIM dense-kernel math (fma association + min tree):
            float t0 = fmaf(qy.x, npy0, fmaf(qx.x, npx0, qz.x));
            float u1 = fmaf(qy.y, npy0, fmaf(qx.y, npx0, qz.y));
            m0 = fminf(m0, fminf(t0, u1));
            float u2 = fmaf(qy.z, npy0, fmaf(qx.z, npx0, qz.z));
            float u3 = fmaf(qy.w, npy0, fmaf(qx.w, npx0, qz.w));
            m0 = fminf(m0, fminf(u2, u3));
            float s0 = fmaf(qy.x, npy1, fmaf(qx.x, npx1, qz.x));
            float s1 = fmaf(qy.y, npy1, fmaf(qx.y, npx1, qz.y));
            m1 = fminf(m1, fminf(s0, s1));
            float s2 = fmaf(qy.z, npy1, fmaf(qx.z, npx1, qz.z));
            float s3 = fmaf(qy.w, npy1, fmaf(qx.w, npx1, qz.w));
            m1 = fminf(m1, fminf(s2, s3));
        }
        __syncthreads();                         // before next overwrite

        if (left) { jlo = max(jb, 0); doneL = doneL || (jlo == 0); }
        else      { jhi = min(jb + 64, n_to); doneR = doneR || (jhi >= n_to); }

        // prune checks (cheap; md recomputed -- matches stored-value form)
        float md0 = v0 ? fmaxf(m0 + p20, 0.0f) : -1.0f;   // invalid: always pruned
        float md1 = v1 ? fmaxf(m1 + p21, 0.0f) : -1.0f;
        if (!doneL) {
            float reL = sqrtf(cols[jlo - 1].z);           // max rho of remaining-left
            float d0 = rho0 - reL, d1 = rho1 - reL;
            bool pl0 = !v0 || ((rho0 > reL) && (d0 * d0 * 0.999f - 0.01f > md0));
            bool pl1 = !v1 || ((rho1 > reL) && (d1 * d1 * 0.999f - 0.01f > md1));
            doneL = __all(pl0 && pl1);
        }
        if (!doneR) {
            float reR = sqrtf(cols[jhi].z);               // min rho of remaining-right
            float d0 = reR - rho0, d1 = reR - rho1;
            bool pr0 = !v0 || ((reR > rho0) && (d0 * d0 * 0.999f - 0.01f > md0));
            bool pr1 = !v1 || ((reR > rho1) && (d1 * d1 * 0.999f - 0.01f > md1));
            doneR = __all(pr0 && pr1);
        }
    }

    // each row resolved by exactly one block: plain stores, no atomics
    if (v0) minarr[combo * HW_ + slot0] = __float_as_uint(fmaxf(m0 + p20, 0.0f));
    if (v1) minarr[combo * HW_ + slot1] = __float_as_uint(fmaxf(m1 + p21, 0.0f));
}

// ---------------- reduce (unchanged: defines the absmax==0 sum order) -------
__global__ void reduce_out_kernel(const int* __restrict__ segcounts,
                                  const unsigned int* __restrict__ minarr,
                                  float* __restrict__ out) {
    int b = blockIdx.x;
    int tid = threadIdx.x;
    int d = tid >> 9;
    int t = tid & 511;
    int combo = b * 2 + d;

    float acc = 0.0f;
    for (int s = 0; s < NSEG; ++s) {
        int c = segcounts[combo * 4 + s];
        const unsigned int* ma = minarr + combo * HW_ + s * SEGCAP;
        for (int r = t; r < c; r += 512)
            acc += sqrtf(fmaxf(__uint_as_float(ma[r]), EPS_));
    }
#pragma unroll
    for (int o = 32; o >= 1; o >>= 1) acc += __shfl_down(acc, o);

    __shared__ float wsum[16];
    if ((tid & 63) == 0) wsum[tid >> 6] = acc;
    __syncthreads();
    if (tid == 0) {
        float s0 = 0.0f, s1 = 0.0f;
#pragma unroll
        for (int w = 0; w < 8; ++w)  s0 += wsum[w];
#pragma unroll
        for (int w = 8; w < 16; ++w) s1 += wsum[w];
        int n0 = 0, n1 = 0;
#pragma unroll
        for (int s = 0; s < NSEG; ++s) {
            n0 += segcounts[(b * 2) * 4 + s];
            n1 += segcounts[(b * 2 + 1) * 4 + s];
        }
        out[b] = (n0 > 0 && n1 > 0)
                 ? s0 / (float)n0 + s1 / (float)n1
                 : 1.0e6f;
    }
}

extern "C" void kernel_launch(void* const* d_in, const int* in_sizes, int n_in,
                              void* d_out, int out_size, void* d_ws, size_t ws_size,
                              hipStream_t stream) {
    const float* in1 = (const float*)d_in[0];
    const float* in2 = (const float*)d_in[1];
    float* out = (float*)d_out;
    char* ws = (char*)d_ws;
    int* segcounts = (int*)ws;
    float4* pts = (float4*)(ws + 256);
    size_t minoff = 256 + (size_t)8 * HW_ * sizeof(float4);
    unsigned int* minarr = (unsigned int*)(ws + minoff);
    size_t sortoff = minoff + (size_t)8 * HW_ * sizeof(unsigned int);
    float4* sorted = (float4*)(ws + sortoff);
    size_t binoff = sortoff + (size_t)8 * HW_ * sizeof(float4);
    int* binstart = (int*)(ws + binoff);

    hipLaunchKernelGGL(compact_kernel, dim3(NSEG, 8), dim3(1024), 0, stream,
                       in1, in2, segcounts, pts, (uint4*)minarr);
    hipLaunchKernelGGL(sort_kernel, dim3(8), dim3(1024), 0, stream,
                       segcounts, pts, sorted, binstart);
    hipLaunchKernelGGL(pdist_kernel, dim3(PD_NGRP, 8), dim3(64), 0, stream,
                       sorted, binstart, minarr);
    hipLaunchKernelGGL(reduce_out_kernel, dim3(B_), dim3(1024), 0, stream,
                       segcounts, minarr, out);
}